// Round 7
// baseline (660.617 us; speedup 1.0000x reference)
//
#include <hip/hip_runtime.h>
#include <math.h>

// Problem constants (from reference): N=100000, E=1600000, D_IN=D_H=128, D_OUT=47
#define DH 128
#define DOUT 47
#define BN_EPS 1e-5f

// ---------------------------------------------------------------------------
// bf16 pack/unpack (RNE). Gather tables are bf16 to halve L2-miss-path bytes;
// accumulation is fp32.
// ---------------------------------------------------------------------------
__device__ __forceinline__ unsigned pack_bf2(float a, float b) {
    unsigned ua = __float_as_uint(a);
    ua = (ua + 0x7fffu + ((ua >> 16) & 1u)) >> 16;
    unsigned ub = __float_as_uint(b);
    ub = (ub + 0x7fffu + ((ub >> 16) & 1u)) >> 16;
    return (ua & 0xffffu) | (ub << 16);
}
__device__ __forceinline__ float2 unpack_bf2(unsigned u) {
    return make_float2(__uint_as_float(u << 16),
                       __uint_as_float(u & 0xffff0000u));
}

// ---------------------------------------------------------------------------
// CSR build helpers
// ---------------------------------------------------------------------------

__global__ void zero_int_k(int* __restrict__ p, int n) {
    int i = blockIdx.x * 256 + threadIdx.x;
    if (i < n) p[i] = 0;
}

__global__ __launch_bounds__(256) void scan1_k(const int* __restrict__ counts,
                                               int* __restrict__ offsets,
                                               int* __restrict__ blocksums, int n) {
    __shared__ int sd[256];
    int tid = threadIdx.x;
    int base = blockIdx.x * 1024 + tid * 4;
    int v0 = (base + 0 < n) ? counts[base + 0] : 0;
    int v1 = (base + 1 < n) ? counts[base + 1] : 0;
    int v2 = (base + 2 < n) ? counts[base + 2] : 0;
    int v3 = (base + 3 < n) ? counts[base + 3] : 0;
    int tsum = v0 + v1 + v2 + v3;
    sd[tid] = tsum;
    __syncthreads();
    for (int off = 1; off < 256; off <<= 1) {
        int x = (tid >= off) ? sd[tid - off] : 0;
        __syncthreads();
        sd[tid] += x;
        __syncthreads();
    }
    if (tid == 255) blocksums[blockIdx.x] = sd[255];
    int run = sd[tid] - tsum;
    if (base + 0 < n) offsets[base + 0] = run;  run += v0;
    if (base + 1 < n) offsets[base + 1] = run;  run += v1;
    if (base + 2 < n) offsets[base + 2] = run;  run += v2;
    if (base + 3 < n) offsets[base + 3] = run;
}

__global__ __launch_bounds__(128) void scan2_k(int* __restrict__ blocksums, int nb) {
    __shared__ int sd[128];
    int tid = threadIdx.x;
    int v = (tid < nb) ? blocksums[tid] : 0;
    sd[tid] = v;
    __syncthreads();
    for (int off = 1; off < 128; off <<= 1) {
        int x = (tid >= off) ? sd[tid - off] : 0;
        __syncthreads();
        sd[tid] += x;
        __syncthreads();
    }
    if (tid < nb) blocksums[tid] = sd[tid] - v;  // exclusive
}

__global__ void finalize_k(int* __restrict__ offsets, int* __restrict__ cursor,
                           float* __restrict__ dinv, const int* __restrict__ counts,
                           const int* __restrict__ blocksums, int n) {
    int i = blockIdx.x * 256 + threadIdx.x;
    if (i >= n) return;
    int o = offsets[i] + blocksums[i >> 10];
    offsets[i] = o;
    cursor[i] = o;
    dinv[i] = rsqrtf((float)(counts[i] + 1));  // +1 self-loop; deg>=1 always
}

// fill: edge record = (src, dinv[src]*dinv[dst]) packed in 8 B.
__global__ void fill_k(const int* __restrict__ src, const int* __restrict__ dst,
                       const float* __restrict__ dinv, int* __restrict__ cursor,
                       int2* __restrict__ ew, int e, int n) {
    int i = blockIdx.x * 256 + threadIdx.x;
    int stride = gridDim.x * 256;
    for (; i < e; i += stride) {
        int d = dst[i];
        if ((unsigned)d < (unsigned)n) {
            int s = src[i];
            int pos = atomicAdd(&cursor[d], 1);
            int2 rec;
            rec.x = s;
            rec.y = __float_as_int(dinv[s] * dinv[d]);
            ew[pos] = rec;
        }
    }
}

// ---------------------------------------------------------------------------
// fp32 GEMM v2: LDS-free register-tile. C[M x 128] = A[M x 128] @ B[128 x 128],
// output packed bf16. No __syncthreads; B served from L2 (64 KB, resident),
// A-row loads are half-wave-uniform (broadcast). Thread (tx,ty) owns
// rows r0+ty*8..+8, cols tx*4..+4.
// ---------------------------------------------------------------------------
#define FMA4(c, s, b) \
    c.x = fmaf(s, b.x, c.x); c.y = fmaf(s, b.y, c.y); \
    c.z = fmaf(s, b.z, c.z); c.w = fmaf(s, b.w, c.w);

#define COUNT_BLOCKS 2048

__device__ __forceinline__ void gemm128_body(const float* __restrict__ A,
                                             const float* __restrict__ B,
                                             unsigned* __restrict__ Cb, int M,
                                             int blk) {
    int tid = threadIdx.x;
    int tx = tid & 31;
    int ty = tid >> 5;
    int r0 = blk * 64;

    // clamped row pointers -> branch-free hot loop (stores still guarded)
    const float* arow[8];
#pragma unroll
    for (int j = 0; j < 8; j++) {
        int r = r0 + ty * 8 + j;
        arow[j] = A + (size_t)(r < M ? r : (M - 1)) * 128;
    }
    const float* bcol = B + tx * 4;

    float4 acc[8];
#pragma unroll
    for (int j = 0; j < 8; j++) acc[j] = make_float4(0.f, 0.f, 0.f, 0.f);

#pragma unroll 2
    for (int k = 0; k < 128; k += 4) {
        float4 b0 = *(const float4*)(bcol + (size_t)(k + 0) * 128);
        float4 b1 = *(const float4*)(bcol + (size_t)(k + 1) * 128);
        float4 b2 = *(const float4*)(bcol + (size_t)(k + 2) * 128);
        float4 b3 = *(const float4*)(bcol + (size_t)(k + 3) * 128);
        float4 a[8];
#pragma unroll
        for (int j = 0; j < 8; j++) a[j] = *(const float4*)(arow[j] + k);
#pragma unroll
        for (int j = 0; j < 8; j++) {
            FMA4(acc[j], a[j].x, b0);
            FMA4(acc[j], a[j].y, b1);
            FMA4(acc[j], a[j].z, b2);
            FMA4(acc[j], a[j].w, b3);
        }
    }

    // epilogue: pack 4 fp32 -> 2 uints (4 bf16), coalesced uint2 stores
#pragma unroll
    for (int j = 0; j < 8; j++) {
        int row = r0 + ty * 8 + j;
        if (row < M) {
            uint2 p;
            p.x = pack_bf2(acc[j].x, acc[j].y);
            p.y = pack_bf2(acc[j].z, acc[j].w);
            *(uint2*)(Cb + (size_t)row * 64 + tx * 2) = p;
        }
    }
}

__global__ __launch_bounds__(256) void gemm128_k(const float* __restrict__ A,
                                                 const float* __restrict__ B,
                                                 unsigned* __restrict__ Cb, int M) {
    gemm128_body(A, B, Cb, M, blockIdx.x);
}

__global__ __launch_bounds__(256) void gemm1_count_k(
    const float* __restrict__ A, const float* __restrict__ B,
    unsigned* __restrict__ Cb, int M, int gemmBlocks,
    const int* __restrict__ dst, int* __restrict__ counts, int e, int n) {
    if ((int)blockIdx.x >= gemmBlocks) {
        int bid = blockIdx.x - gemmBlocks;
        int i = bid * 256 + threadIdx.x;
        int stride = COUNT_BLOCKS * 256;
        for (; i < e; i += stride) {
            int d = dst[i];
            if ((unsigned)d < (unsigned)n) atomicAdd(&counts[d], 1);
        }
        return;
    }
    gemm128_body(A, B, Cb, M, blockIdx.x);
}

// ---------------------------------------------------------------------------
// Aggregation core: one 64-lane wave per node; each lane owns 2 features,
// loaded as one uint (bf16 pair) per gathered row -> 256 B/row on the
// L2-miss path. fp32 accumulate. 3-stage pipeline with masked loads;
// ew padded by 16 records.
// ---------------------------------------------------------------------------
__device__ __forceinline__ float2 agg_core(const unsigned* __restrict__ Hrow,
                                           const int2* __restrict__ ew,
                                           int start, int cnt, int node,
                                           int lane, float di) {
    float2 self = unpack_bf2(Hrow[(size_t)node * 64 + lane]);
    float wself = di * di;
    float2 acc = make_float2(self.x * wself, self.y * wself);
    if (cnt <= 0) return acc;

    const int2* ep = ew + start;
    int iters = (cnt + 3) >> 2;

    unsigned fC[4];
    float wC[4];
    int2 eN[4];
    {
        int2 e0[4];
#pragma unroll
        for (int k = 0; k < 4; k++) e0[k] = ep[k];
#pragma unroll
        for (int k = 0; k < 4; k++) {
            bool v = k < cnt;
            int s = v ? e0[k].x : 0;
            wC[k] = v ? __int_as_float(e0[k].y) : 0.f;
            fC[k] = Hrow[(size_t)s * 64 + lane];
        }
#pragma unroll
        for (int k = 0; k < 4; k++) eN[k] = ep[4 + k];
    }

    for (int g = 0; g < iters; ++g) {
        unsigned fN[4];
        float wN[4];
        int bN = (g + 1) << 2;
#pragma unroll
        for (int k = 0; k < 4; k++) {
            bool v = (bN + k) < cnt;
            int s = v ? eN[k].x : 0;
            wN[k] = v ? __int_as_float(eN[k].y) : 0.f;
            fN[k] = Hrow[(size_t)s * 64 + lane];
        }
#pragma unroll
        for (int k = 0; k < 4; k++) eN[k] = ep[bN + 4 + k];
#pragma unroll
        for (int k = 0; k < 4; k++) {
            float2 f = unpack_bf2(fC[k]);
            acc.x = fmaf(f.x, wC[k], acc.x);
            acc.y = fmaf(f.y, wC[k], acc.y);
        }
#pragma unroll
        for (int k = 0; k < 4; k++) { fC[k] = fN[k]; wC[k] = wN[k]; }
    }
    return acc;
}

// Layer 1: + b1, BN(eval), ReLU -> H1 (fp32)
__global__ __launch_bounds__(256) void agg1_k(
    const unsigned* __restrict__ H, const int2* __restrict__ ew,
    const int* __restrict__ offsets, const int* __restrict__ counts,
    const float* __restrict__ dinv, const float* __restrict__ b1,
    const float* __restrict__ gamma, const float* __restrict__ beta,
    const float* __restrict__ mean, const float* __restrict__ var,
    float* __restrict__ H1, int n) {
    int lane = threadIdx.x & 63;
    int node = blockIdx.x * 4 + (threadIdx.x >> 6);
    if (node >= n) return;
    float2 acc = agg_core(H, ew, offsets[node], counts[node],
                          node, lane, dinv[node]);
    int t0 = lane * 2;
    float2 bb = *(const float2*)(b1 + t0);
    float2 mm = *(const float2*)(mean + t0);
    float2 vv = *(const float2*)(var + t0);
    float2 gg = *(const float2*)(gamma + t0);
    float2 be = *(const float2*)(beta + t0);
    float vx = (acc.x + bb.x - mm.x) * rsqrtf(vv.x + BN_EPS) * gg.x + be.x;
    float vy = (acc.y + bb.y - mm.y) * rsqrtf(vv.y + BN_EPS) * gg.y + be.y;
    float2 outv = make_float2(fmaxf(vx, 0.f), fmaxf(vy, 0.f));
    *(float2*)(H1 + (size_t)node * 128 + t0) = outv;
}

// Layer 2: + b2, then JK max with H1 (in-place H1 -> JK)
__global__ __launch_bounds__(256) void agg2_k(
    const unsigned* __restrict__ H, const int2* __restrict__ ew,
    const int* __restrict__ offsets, const int* __restrict__ counts,
    const float* __restrict__ dinv, const float* __restrict__ b2,
    float* __restrict__ H1JK, int n) {
    int lane = threadIdx.x & 63;
    int node = blockIdx.x * 4 + (threadIdx.x >> 6);
    if (node >= n) return;
    float2 acc = agg_core(H, ew, offsets[node], counts[node],
                          node, lane, dinv[node]);
    int t0 = lane * 2;
    float2 bb = *(const float2*)(b2 + t0);
    float2* p = (float2*)(H1JK + (size_t)node * 128 + t0);
    float2 h1v = *p;
    float2 outv = make_float2(fmaxf(h1v.x, acc.x + bb.x),
                              fmaxf(h1v.y, acc.y + bb.y));
    *p = outv;
}

// ---------------------------------------------------------------------------
// Head: tiled GEMM (64 nodes x 48 cols, K=128) + fused log_softmax.
// ---------------------------------------------------------------------------
__global__ __launch_bounds__(256) void head_k(const float* __restrict__ JK,
                                              const float* __restrict__ Wf,
                                              const float* __restrict__ bf,
                                              float* __restrict__ out, int n) {
    __shared__ __align__(16) float Bs[48 * 132];  // [col][k], stride 132
    __shared__ __align__(16) float As[64 * 36];   // [row][k-in-panel], stride 36
    int tid = threadIdx.x;
    for (int p = tid; p < 47 * 32; p += 256) {
        int c = p >> 5;          // 0..46
        int k0 = (p & 31) << 2;  // 0,4,...,124
        float4 v;
        v.x = Wf[(size_t)(k0 + 0) * DOUT + c];
        v.y = Wf[(size_t)(k0 + 1) * DOUT + c];
        v.z = Wf[(size_t)(k0 + 2) * DOUT + c];
        v.w = Wf[(size_t)(k0 + 3) * DOUT + c];
        *(float4*)(&Bs[c * 132 + k0]) = v;
    }
    int tx = tid & 15;   // col group: cols [3*tx, 3*tx+3)
    int ty = tid >> 4;   // row group: rows [4*ty, 4*ty+4)
    int node0 = blockIdx.x * 64;

    float acc[4][3];
#pragma unroll
    for (int i = 0; i < 4; i++)
#pragma unroll
        for (int j = 0; j < 3; j++) acc[i][j] = 0.f;

    for (int kk = 0; kk < 128; kk += 32) {
        __syncthreads();
        for (int l = tid; l < 512; l += 256) {
            int r = l >> 3;
            int c4 = (l & 7) << 2;
            int row = node0 + r;
            float4 v = make_float4(0.f, 0.f, 0.f, 0.f);
            if (row < n) v = *(const float4*)(JK + (size_t)row * 128 + kk + c4);
            *(float4*)(&As[r * 36 + c4]) = v;
        }
        __syncthreads();
#pragma unroll
        for (int k4 = 0; k4 < 32; k4 += 4) {
            float4 a0 = *(const float4*)(&As[(ty * 4 + 0) * 36 + k4]);
            float4 a1 = *(const float4*)(&As[(ty * 4 + 1) * 36 + k4]);
            float4 a2 = *(const float4*)(&As[(ty * 4 + 2) * 36 + k4]);
            float4 a3 = *(const float4*)(&As[(ty * 4 + 3) * 36 + k4]);
            float4 b0 = *(const float4*)(&Bs[(tx * 3 + 0) * 132 + kk + k4]);
            float4 b1 = *(const float4*)(&Bs[(tx * 3 + 1) * 132 + kk + k4]);
            float4 b2 = *(const float4*)(&Bs[(tx * 3 + 2) * 132 + kk + k4]);
#define DOT_ROW(i, a)                                                        \
            acc[i][0] = fmaf(a.x, b0.x, acc[i][0]);                          \
            acc[i][0] = fmaf(a.y, b0.y, acc[i][0]);                          \
            acc[i][0] = fmaf(a.z, b0.z, acc[i][0]);                          \
            acc[i][0] = fmaf(a.w, b0.w, acc[i][0]);                          \
            acc[i][1] = fmaf(a.x, b1.x, acc[i][1]);                          \
            acc[i][1] = fmaf(a.y, b1.y, acc[i][1]);                          \
            acc[i][1] = fmaf(a.z, b1.z, acc[i][1]);                          \
            acc[i][1] = fmaf(a.w, b1.w, acc[i][1]);                          \
            acc[i][2] = fmaf(a.x, b2.x, acc[i][2]);                          \
            acc[i][2] = fmaf(a.y, b2.y, acc[i][2]);                          \
            acc[i][2] = fmaf(a.z, b2.z, acc[i][2]);                          \
            acc[i][2] = fmaf(a.w, b2.w, acc[i][2]);
            DOT_ROW(0, a0)
            DOT_ROW(1, a1)
            DOT_ROW(2, a2)
            DOT_ROW(3, a3)
#undef DOT_ROW
        }
    }

    float bfv[3];
#pragma unroll
    for (int j = 0; j < 3; j++) {
        int c = tx * 3 + j;
        bfv[j] = (c < DOUT) ? bf[c] : 0.f;
    }
#pragma unroll
    for (int i = 0; i < 4; i++) {
        int node = node0 + ty * 4 + i;
        float l0 = acc[i][0] + bfv[0];
        float l1 = acc[i][1] + bfv[1];
        float l2 = acc[i][2] + bfv[2];
        bool v2ok = (tx * 3 + 2) < DOUT;  // only col 47 (tx=15,j=2) invalid
        float m = fmaxf(l0, l1);
        if (v2ok) m = fmaxf(m, l2);
        for (int off = 8; off >= 1; off >>= 1) m = fmaxf(m, __shfl_xor(m, off));
        float s = expf(l0 - m) + expf(l1 - m) + (v2ok ? expf(l2 - m) : 0.f);
        for (int off = 8; off >= 1; off >>= 1) s += __shfl_xor(s, off);
        float ls = m + logf(s);
        if (node < n) {
            float* o = out + (size_t)node * DOUT + tx * 3;
            o[0] = l0 - ls;
            o[1] = l1 - ls;
            if (v2ok) o[2] = l2 - ls;
        }
    }
}

// ---------------------------------------------------------------------------
extern "C" void kernel_launch(void* const* d_in, const int* in_sizes, int n_in,
                              void* d_out, int out_size, void* d_ws, size_t ws_size,
                              hipStream_t stream) {
    const float* x     = (const float*)d_in[0];
    const int*   ei    = (const int*)d_in[1];
    const float* W1    = (const float*)d_in[2];
    const float* b1    = (const float*)d_in[3];
    const float* gamma = (const float*)d_in[4];
    const float* beta  = (const float*)d_in[5];
    const float* mean  = (const float*)d_in[6];
    const float* var   = (const float*)d_in[7];
    const float* W2    = (const float*)d_in[8];
    const float* b2    = (const float*)d_in[9];
    const float* Wf    = (const float*)d_in[10];
    const float* bf    = (const float*)d_in[11];
    float* out = (float*)d_out;

    int N_ = in_sizes[0] / 128;
    int E_ = in_sizes[1] / 2;
    const int* src = ei;
    const int* dst = ei + E_;

    char* ws = (char*)d_ws;
    unsigned* bufA = (unsigned*)ws; ws += (size_t)N_ * 64 * 4;  // bf16 table (128 feats x 2B)
    float* h1      = (float*)ws;  ws += (size_t)N_ * 128 * 4;
    int*   counts  = (int*)ws;    ws += (size_t)N_ * 4;
    int*   offsets = (int*)ws;    ws += (size_t)N_ * 4;
    int*   cursor  = (int*)ws;    ws += (size_t)N_ * 4;
    float* dinv    = (float*)ws;  ws += (size_t)N_ * 4;
    int2*  ew      = (int2*)ws;   ws += ((size_t)E_ + 16) * 8;  // +16 pad for pipeline prefetch
    int*   bsums   = (int*)ws;    ws += 1024 * 4;

    int nb = (N_ + 1023) / 1024;
    int gemmBlocks = (N_ + 63) / 64;

    zero_int_k<<<(N_ + 255) / 256, 256, 0, stream>>>(counts, N_);
    // layer-1 GEMM with edge-count histogram fused in (independent work)
    gemm1_count_k<<<gemmBlocks + COUNT_BLOCKS, 256, 0, stream>>>(
        x, W1, bufA, N_, gemmBlocks, dst, counts, E_, N_);
    scan1_k<<<nb, 256, 0, stream>>>(counts, offsets, bsums, N_);
    scan2_k<<<1, 128, 0, stream>>>(bsums, nb);
    finalize_k<<<(N_ + 255) / 256, 256, 0, stream>>>(offsets, cursor, dinv, counts, bsums, N_);
    fill_k<<<2048, 256, 0, stream>>>(src, dst, dinv, cursor, ew, E_, N_);

    agg1_k<<<(N_ + 3) / 4, 256, 0, stream>>>(bufA, ew, offsets, counts, dinv,
                                             b1, gamma, beta, mean, var, h1, N_);
    // layer 2 (reuse bufA)
    gemm128_k<<<gemmBlocks, 256, 0, stream>>>(h1, W2, bufA, N_);
    agg2_k<<<(N_ + 3) / 4, 256, 0, stream>>>(bufA, ew, offsets, counts, dinv,
                                             b2, h1, N_);
    // head: h1 now holds jk = max(h1, h2); 64 nodes per block
    head_k<<<(N_ + 63) / 64, 256, 0, stream>>>(h1, Wf, bf, out, N_);
}

// Round 8
// 505.962 us; speedup vs baseline: 1.3057x; 1.3057x over previous
//
#include <hip/hip_runtime.h>
#include <math.h>

// Problem constants (from reference): N=100000, E=1600000, D_IN=D_H=128, D_OUT=47
#define DH 128
#define DOUT 47
#define BN_EPS 1e-5f

typedef __attribute__((ext_vector_type(8))) short short8;
typedef __attribute__((ext_vector_type(4))) float float4v;

// ---------------------------------------------------------------------------
// bf16 pack/unpack (RNE).
// ---------------------------------------------------------------------------
__device__ __forceinline__ unsigned bf16_rne(float f) {
    unsigned u = __float_as_uint(f);
    return (u + 0x7fffu + ((u >> 16) & 1u)) >> 16;
}
__device__ __forceinline__ unsigned pack_bf2(float a, float b) {
    return (bf16_rne(a) & 0xffffu) | (bf16_rne(b) << 16);
}
__device__ __forceinline__ float2 unpack_bf2(unsigned u) {
    return make_float2(__uint_as_float(u << 16),
                       __uint_as_float(u & 0xffff0000u));
}

// ---------------------------------------------------------------------------
// CSR build helpers
// ---------------------------------------------------------------------------

__global__ void zero_int_k(int* __restrict__ p, int n) {
    int i = blockIdx.x * 256 + threadIdx.x;
    if (i < n) p[i] = 0;
}

__global__ __launch_bounds__(256) void scan1_k(const int* __restrict__ counts,
                                               int* __restrict__ offsets,
                                               int* __restrict__ blocksums, int n) {
    __shared__ int sd[256];
    int tid = threadIdx.x;
    int base = blockIdx.x * 1024 + tid * 4;
    int v0 = (base + 0 < n) ? counts[base + 0] : 0;
    int v1 = (base + 1 < n) ? counts[base + 1] : 0;
    int v2 = (base + 2 < n) ? counts[base + 2] : 0;
    int v3 = (base + 3 < n) ? counts[base + 3] : 0;
    int tsum = v0 + v1 + v2 + v3;
    sd[tid] = tsum;
    __syncthreads();
    for (int off = 1; off < 256; off <<= 1) {
        int x = (tid >= off) ? sd[tid - off] : 0;
        __syncthreads();
        sd[tid] += x;
        __syncthreads();
    }
    if (tid == 255) blocksums[blockIdx.x] = sd[255];
    int run = sd[tid] - tsum;
    if (base + 0 < n) offsets[base + 0] = run;  run += v0;
    if (base + 1 < n) offsets[base + 1] = run;  run += v1;
    if (base + 2 < n) offsets[base + 2] = run;  run += v2;
    if (base + 3 < n) offsets[base + 3] = run;
}

__global__ __launch_bounds__(128) void scan2_k(int* __restrict__ blocksums, int nb) {
    __shared__ int sd[128];
    int tid = threadIdx.x;
    int v = (tid < nb) ? blocksums[tid] : 0;
    sd[tid] = v;
    __syncthreads();
    for (int off = 1; off < 128; off <<= 1) {
        int x = (tid >= off) ? sd[tid - off] : 0;
        __syncthreads();
        sd[tid] += x;
        __syncthreads();
    }
    if (tid < nb) blocksums[tid] = sd[tid] - v;  // exclusive
}

__global__ void finalize_k(int* __restrict__ offsets, int* __restrict__ cursor,
                           float* __restrict__ dinv, const int* __restrict__ counts,
                           const int* __restrict__ blocksums, int n) {
    int i = blockIdx.x * 256 + threadIdx.x;
    if (i >= n) return;
    int o = offsets[i] + blocksums[i >> 10];
    offsets[i] = o;
    cursor[i] = o;
    dinv[i] = rsqrtf((float)(counts[i] + 1));  // +1 self-loop; deg>=1 always
}

// fill: edge record = (src, dinv[src]*dinv[dst]) packed in 8 B.
__global__ void fill_k(const int* __restrict__ src, const int* __restrict__ dst,
                       const float* __restrict__ dinv, int* __restrict__ cursor,
                       int2* __restrict__ ew, int e, int n) {
    int i = blockIdx.x * 256 + threadIdx.x;
    int stride = gridDim.x * 256;
    for (; i < e; i += stride) {
        int d = dst[i];
        if ((unsigned)d < (unsigned)n) {
            int s = src[i];
            int pos = atomicAdd(&cursor[d], 1);
            int2 rec;
            rec.x = s;
            rec.y = __float_as_int(dinv[s] * dinv[d]);
            ew[pos] = rec;
        }
    }
}

// ---------------------------------------------------------------------------
// Weight prep: W fp32 [k][n] -> bf16 transposed [n][k] (64 uints/row).
// grid 2: block 0 -> W1, block 1 -> W2.
// ---------------------------------------------------------------------------
__global__ __launch_bounds__(256) void wprep_k(const float* __restrict__ W1,
                                               const float* __restrict__ W2,
                                               unsigned* __restrict__ W1b,
                                               unsigned* __restrict__ W2b) {
    const float* W = blockIdx.x ? W2 : W1;
    unsigned* Wb = blockIdx.x ? W2b : W1b;
    int tid = threadIdx.x;
    for (int p = tid; p < 128 * 32; p += 256) {
        int n = p >> 5;
        int k0 = (p & 31) << 2;
        float f0 = W[(size_t)(k0 + 0) * 128 + n];
        float f1 = W[(size_t)(k0 + 1) * 128 + n];
        float f2 = W[(size_t)(k0 + 2) * 128 + n];
        float f3 = W[(size_t)(k0 + 3) * 128 + n];
        uint2 v;
        v.x = pack_bf2(f0, f1);
        v.y = pack_bf2(f2, f3);
        *(uint2*)(Wb + (size_t)n * 64 + (k0 >> 1)) = v;
    }
}

// ---------------------------------------------------------------------------
// MFMA GEMM: C[M x 128] = A[M x 128] @ W[128 x 128], A fp32 split hi/lo bf16
// in-register (2 mfma per tile -> near-fp32 A precision), W pre-quantized
// bf16 [n][k] staged whole into LDS (one barrier). Output packed bf16 table.
// Per block: 64 rows, 4 waves x 16 rows; wave does 8 n-tiles x 4 k-panels
// with mfma_f32_16x16x32_bf16. Fragment layouts per cdna4 guide S3 (m89/m91):
//   A: m=lane&15, k=quad*8+j ; B: n=lane&15, k=quad*8+j ; C: col=lane&15,
//   row=quad*4+reg.
// ---------------------------------------------------------------------------
#define COUNT_BLOCKS 2048

__device__ __forceinline__ void gemm_mfma_body(const float* __restrict__ A,
                                               const unsigned* __restrict__ Wb,
                                               unsigned* __restrict__ Cb, int M,
                                               int blk) {
    __shared__ ushort Bl[128 * 136];  // [n][k] bf16, pad 8 -> 2-way-max banks
    int tid = threadIdx.x;
    {
        unsigned* Bu = (unsigned*)Bl;
        for (int q = tid; q < 128 * 16; q += 256) {
            int row = q >> 4;
            int c = (q & 15) << 2;
            uint4 v = *(const uint4*)(Wb + (size_t)row * 64 + c);
            *(uint4*)(Bu + (size_t)row * 68 + c) = v;
        }
    }
    __syncthreads();

    int lane = tid & 63;
    int wv = tid >> 6;
    int quad = lane >> 4;
    int l15 = lane & 15;
    int r0 = blk * 64 + wv * 16;
    int mload = r0 + l15;
    if (mload > M - 1) mload = M - 1;
    const float* Ar = A + (size_t)mload * 128 + quad * 8;

    float4v acc[8];
#pragma unroll
    for (int t = 0; t < 8; t++) acc[t] = (float4v){0.f, 0.f, 0.f, 0.f};

    for (int kp = 0; kp < 4; ++kp) {
        float4 a0 = *(const float4*)(Ar + kp * 32);
        float4 a1 = *(const float4*)(Ar + kp * 32 + 4);
        float af[8] = {a0.x, a0.y, a0.z, a0.w, a1.x, a1.y, a1.z, a1.w};
        short8 hi, lo;
#pragma unroll
        for (int j = 0; j < 8; j++) {
            unsigned h = bf16_rne(af[j]);
            hi[j] = (short)h;
            float res = af[j] - __uint_as_float(h << 16);
            lo[j] = (short)bf16_rne(res);
        }
        int kb = kp * 32 + quad * 8;
#pragma unroll
        for (int nt = 0; nt < 8; nt++) {
            short8 b8 = *(const short8*)(&Bl[(size_t)(nt * 16 + l15) * 136 + kb]);
            acc[nt] = __builtin_amdgcn_mfma_f32_16x16x32_bf16(hi, b8, acc[nt], 0, 0, 0);
            acc[nt] = __builtin_amdgcn_mfma_f32_16x16x32_bf16(lo, b8, acc[nt], 0, 0, 0);
        }
    }

    // epilogue: row = r0 + quad*4 + r, col = nt*16 + l15; scalar bf16 stores
    ushort* Cu = (ushort*)Cb;
#pragma unroll
    for (int r = 0; r < 4; r++) {
        int row = r0 + quad * 4 + r;
        if (row < M) {
#pragma unroll
            for (int nt = 0; nt < 8; nt++) {
                Cu[(size_t)row * 128 + nt * 16 + l15] = (ushort)bf16_rne(acc[nt][r]);
            }
        }
    }
}

__global__ __launch_bounds__(256) void gemm_mfma_k(const float* __restrict__ A,
                                                   const unsigned* __restrict__ Wb,
                                                   unsigned* __restrict__ Cb, int M) {
    gemm_mfma_body(A, Wb, Cb, M, blockIdx.x);
}

__global__ __launch_bounds__(256) void gemm1_count_k(
    const float* __restrict__ A, const unsigned* __restrict__ Wb,
    unsigned* __restrict__ Cb, int M, int gemmBlocks,
    const int* __restrict__ dst, int* __restrict__ counts, int e, int n) {
    if ((int)blockIdx.x >= gemmBlocks) {
        int bid = blockIdx.x - gemmBlocks;
        int i = bid * 256 + threadIdx.x;
        int stride = COUNT_BLOCKS * 256;
        for (; i < e; i += stride) {
            int d = dst[i];
            if ((unsigned)d < (unsigned)n) atomicAdd(&counts[d], 1);
        }
        return;
    }
    gemm_mfma_body(A, Wb, Cb, M, blockIdx.x);
}

// ---------------------------------------------------------------------------
// Aggregation core: one 64-lane wave per node; lane owns 2 features (one uint
// bf16 pair per gathered row -> 256 B/row on the L2-miss path). fp32 accum.
// 3-stage pipeline with masked loads; ew padded by 16 records.
// ---------------------------------------------------------------------------
__device__ __forceinline__ float2 agg_core(const unsigned* __restrict__ Hrow,
                                           const int2* __restrict__ ew,
                                           int start, int cnt, int node,
                                           int lane, float di) {
    float2 self = unpack_bf2(Hrow[(size_t)node * 64 + lane]);
    float wself = di * di;
    float2 acc = make_float2(self.x * wself, self.y * wself);
    if (cnt <= 0) return acc;

    const int2* ep = ew + start;
    int iters = (cnt + 3) >> 2;

    unsigned fC[4];
    float wC[4];
    int2 eN[4];
    {
        int2 e0[4];
#pragma unroll
        for (int k = 0; k < 4; k++) e0[k] = ep[k];
#pragma unroll
        for (int k = 0; k < 4; k++) {
            bool v = k < cnt;
            int s = v ? e0[k].x : 0;
            wC[k] = v ? __int_as_float(e0[k].y) : 0.f;
            fC[k] = Hrow[(size_t)s * 64 + lane];
        }
#pragma unroll
        for (int k = 0; k < 4; k++) eN[k] = ep[4 + k];
    }

    for (int g = 0; g < iters; ++g) {
        unsigned fN[4];
        float wN[4];
        int bN = (g + 1) << 2;
#pragma unroll
        for (int k = 0; k < 4; k++) {
            bool v = (bN + k) < cnt;
            int s = v ? eN[k].x : 0;
            wN[k] = v ? __int_as_float(eN[k].y) : 0.f;
            fN[k] = Hrow[(size_t)s * 64 + lane];
        }
#pragma unroll
        for (int k = 0; k < 4; k++) eN[k] = ep[bN + 4 + k];
#pragma unroll
        for (int k = 0; k < 4; k++) {
            float2 f = unpack_bf2(fC[k]);
            acc.x = fmaf(f.x, wC[k], acc.x);
            acc.y = fmaf(f.y, wC[k], acc.y);
        }
#pragma unroll
        for (int k = 0; k < 4; k++) { fC[k] = fN[k]; wC[k] = wN[k]; }
    }
    return acc;
}

// Layer 1: + b1, BN(eval), ReLU -> H1 (fp32)
__global__ __launch_bounds__(256) void agg1_k(
    const unsigned* __restrict__ H, const int2* __restrict__ ew,
    const int* __restrict__ offsets, const int* __restrict__ counts,
    const float* __restrict__ dinv, const float* __restrict__ b1,
    const float* __restrict__ gamma, const float* __restrict__ beta,
    const float* __restrict__ mean, const float* __restrict__ var,
    float* __restrict__ H1, int n) {
    int lane = threadIdx.x & 63;
    int node = blockIdx.x * 4 + (threadIdx.x >> 6);
    if (node >= n) return;
    float2 acc = agg_core(H, ew, offsets[node], counts[node],
                          node, lane, dinv[node]);
    int t0 = lane * 2;
    float2 bb = *(const float2*)(b1 + t0);
    float2 mm = *(const float2*)(mean + t0);
    float2 vv = *(const float2*)(var + t0);
    float2 gg = *(const float2*)(gamma + t0);
    float2 be = *(const float2*)(beta + t0);
    float vx = (acc.x + bb.x - mm.x) * rsqrtf(vv.x + BN_EPS) * gg.x + be.x;
    float vy = (acc.y + bb.y - mm.y) * rsqrtf(vv.y + BN_EPS) * gg.y + be.y;
    float2 outv = make_float2(fmaxf(vx, 0.f), fmaxf(vy, 0.f));
    *(float2*)(H1 + (size_t)node * 128 + t0) = outv;
}

// Layer 2: + b2, then JK max with H1 (in-place H1 -> JK)
__global__ __launch_bounds__(256) void agg2_k(
    const unsigned* __restrict__ H, const int2* __restrict__ ew,
    const int* __restrict__ offsets, const int* __restrict__ counts,
    const float* __restrict__ dinv, const float* __restrict__ b2,
    float* __restrict__ H1JK, int n) {
    int lane = threadIdx.x & 63;
    int node = blockIdx.x * 4 + (threadIdx.x >> 6);
    if (node >= n) return;
    float2 acc = agg_core(H, ew, offsets[node], counts[node],
                          node, lane, dinv[node]);
    int t0 = lane * 2;
    float2 bb = *(const float2*)(b2 + t0);
    float2* p = (float2*)(H1JK + (size_t)node * 128 + t0);
    float2 h1v = *p;
    float2 outv = make_float2(fmaxf(h1v.x, acc.x + bb.x),
                              fmaxf(h1v.y, acc.y + bb.y));
    *p = outv;
}

// ---------------------------------------------------------------------------
// Head: tiled GEMM (64 nodes x 48 cols, K=128) + fused log_softmax.
// ---------------------------------------------------------------------------
__global__ __launch_bounds__(256) void head_k(const float* __restrict__ JK,
                                              const float* __restrict__ Wf,
                                              const float* __restrict__ bf,
                                              float* __restrict__ out, int n) {
    __shared__ __align__(16) float Bs[48 * 132];  // [col][k], stride 132
    __shared__ __align__(16) float As[64 * 36];   // [row][k-in-panel], stride 36
    int tid = threadIdx.x;
    for (int p = tid; p < 47 * 32; p += 256) {
        int c = p >> 5;          // 0..46
        int k0 = (p & 31) << 2;  // 0,4,...,124
        float4 v;
        v.x = Wf[(size_t)(k0 + 0) * DOUT + c];
        v.y = Wf[(size_t)(k0 + 1) * DOUT + c];
        v.z = Wf[(size_t)(k0 + 2) * DOUT + c];
        v.w = Wf[(size_t)(k0 + 3) * DOUT + c];
        *(float4*)(&Bs[c * 132 + k0]) = v;
    }
    int tx = tid & 15;   // col group: cols [3*tx, 3*tx+3)
    int ty = tid >> 4;   // row group: rows [4*ty, 4*ty+4)
    int node0 = blockIdx.x * 64;

    float acc[4][3];
#pragma unroll
    for (int i = 0; i < 4; i++)
#pragma unroll
        for (int j = 0; j < 3; j++) acc[i][j] = 0.f;

    for (int kk = 0; kk < 128; kk += 32) {
        __syncthreads();
        for (int l = tid; l < 512; l += 256) {
            int r = l >> 3;
            int c4 = (l & 7) << 2;
            int row = node0 + r;
            float4 v = make_float4(0.f, 0.f, 0.f, 0.f);
            if (row < n) v = *(const float4*)(JK + (size_t)row * 128 + kk + c4);
            *(float4*)(&As[r * 36 + c4]) = v;
        }
        __syncthreads();
#pragma unroll
        for (int k4 = 0; k4 < 32; k4 += 4) {
            float4 a0 = *(const float4*)(&As[(ty * 4 + 0) * 36 + k4]);
            float4 a1 = *(const float4*)(&As[(ty * 4 + 1) * 36 + k4]);
            float4 a2 = *(const float4*)(&As[(ty * 4 + 2) * 36 + k4]);
            float4 a3 = *(const float4*)(&As[(ty * 4 + 3) * 36 + k4]);
            float4 b0 = *(const float4*)(&Bs[(tx * 3 + 0) * 132 + kk + k4]);
            float4 b1 = *(const float4*)(&Bs[(tx * 3 + 1) * 132 + kk + k4]);
            float4 b2 = *(const float4*)(&Bs[(tx * 3 + 2) * 132 + kk + k4]);
#define DOT_ROW(i, a)                                                        \
            acc[i][0] = fmaf(a.x, b0.x, acc[i][0]);                          \
            acc[i][0] = fmaf(a.y, b0.y, acc[i][0]);                          \
            acc[i][0] = fmaf(a.z, b0.z, acc[i][0]);                          \
            acc[i][0] = fmaf(a.w, b0.w, acc[i][0]);                          \
            acc[i][1] = fmaf(a.x, b1.x, acc[i][1]);                          \
            acc[i][1] = fmaf(a.y, b1.y, acc[i][1]);                          \
            acc[i][1] = fmaf(a.z, b1.z, acc[i][1]);                          \
            acc[i][1] = fmaf(a.w, b1.w, acc[i][1]);                          \
            acc[i][2] = fmaf(a.x, b2.x, acc[i][2]);                          \
            acc[i][2] = fmaf(a.y, b2.y, acc[i][2]);                          \
            acc[i][2] = fmaf(a.z, b2.z, acc[i][2]);                          \
            acc[i][2] = fmaf(a.w, b2.w, acc[i][2]);
            DOT_ROW(0, a0)
            DOT_ROW(1, a1)
            DOT_ROW(2, a2)
            DOT_ROW(3, a3)
#undef DOT_ROW
        }
    }

    float bfv[3];
#pragma unroll
    for (int j = 0; j < 3; j++) {
        int c = tx * 3 + j;
        bfv[j] = (c < DOUT) ? bf[c] : 0.f;
    }
#pragma unroll
    for (int i = 0; i < 4; i++) {
        int node = node0 + ty * 4 + i;
        float l0 = acc[i][0] + bfv[0];
        float l1 = acc[i][1] + bfv[1];
        float l2 = acc[i][2] + bfv[2];
        bool v2ok = (tx * 3 + 2) < DOUT;  // only col 47 (tx=15,j=2) invalid
        float m = fmaxf(l0, l1);
        if (v2ok) m = fmaxf(m, l2);
        for (int off = 8; off >= 1; off >>= 1) m = fmaxf(m, __shfl_xor(m, off));
        float s = expf(l0 - m) + expf(l1 - m) + (v2ok ? expf(l2 - m) : 0.f);
        for (int off = 8; off >= 1; off >>= 1) s += __shfl_xor(s, off);
        float ls = m + logf(s);
        if (node < n) {
            float* o = out + (size_t)node * DOUT + tx * 3;
            o[0] = l0 - ls;
            o[1] = l1 - ls;
            if (v2ok) o[2] = l2 - ls;
        }
    }
}

// ---------------------------------------------------------------------------
extern "C" void kernel_launch(void* const* d_in, const int* in_sizes, int n_in,
                              void* d_out, int out_size, void* d_ws, size_t ws_size,
                              hipStream_t stream) {
    const float* x     = (const float*)d_in[0];
    const int*   ei    = (const int*)d_in[1];
    const float* W1    = (const float*)d_in[2];
    const float* b1    = (const float*)d_in[3];
    const float* gamma = (const float*)d_in[4];
    const float* beta  = (const float*)d_in[5];
    const float* mean  = (const float*)d_in[6];
    const float* var   = (const float*)d_in[7];
    const float* W2    = (const float*)d_in[8];
    const float* b2    = (const float*)d_in[9];
    const float* Wf    = (const float*)d_in[10];
    const float* bf    = (const float*)d_in[11];
    float* out = (float*)d_out;

    int N_ = in_sizes[0] / 128;
    int E_ = in_sizes[1] / 2;
    const int* src = ei;
    const int* dst = ei + E_;

    char* ws = (char*)d_ws;
    unsigned* bufA = (unsigned*)ws; ws += (size_t)N_ * 64 * 4;  // bf16 table (128 feats x 2B)
    float* h1      = (float*)ws;  ws += (size_t)N_ * 128 * 4;
    int*   counts  = (int*)ws;    ws += (size_t)N_ * 4;
    int*   offsets = (int*)ws;    ws += (size_t)N_ * 4;
    int*   cursor  = (int*)ws;    ws += (size_t)N_ * 4;
    float* dinv    = (float*)ws;  ws += (size_t)N_ * 4;
    int2*  ew      = (int2*)ws;   ws += ((size_t)E_ + 16) * 8;  // +16 pad for pipeline prefetch
    int*   bsums   = (int*)ws;    ws += 1024 * 4;
    unsigned* W1b  = (unsigned*)ws; ws += 128 * 64 * 4;         // bf16 W^T [n][k]
    unsigned* W2b  = (unsigned*)ws; ws += 128 * 64 * 4;

    int nb = (N_ + 1023) / 1024;
    int gemmBlocks = (N_ + 63) / 64;

    zero_int_k<<<(N_ + 255) / 256, 256, 0, stream>>>(counts, N_);
    wprep_k<<<2, 256, 0, stream>>>(W1, W2, W1b, W2b);
    // layer-1 MFMA GEMM with edge-count histogram fused in
    gemm1_count_k<<<gemmBlocks + COUNT_BLOCKS, 256, 0, stream>>>(
        x, W1b, bufA, N_, gemmBlocks, dst, counts, E_, N_);
    scan1_k<<<nb, 256, 0, stream>>>(counts, offsets, bsums, N_);
    scan2_k<<<1, 128, 0, stream>>>(bsums, nb);
    finalize_k<<<(N_ + 255) / 256, 256, 0, stream>>>(offsets, cursor, dinv, counts, bsums, N_);
    fill_k<<<2048, 256, 0, stream>>>(src, dst, dinv, cursor, ew, E_, N_);

    agg1_k<<<(N_ + 3) / 4, 256, 0, stream>>>(bufA, ew, offsets, counts, dinv,
                                             b1, gamma, beta, mean, var, h1, N_);
    // layer 2 (reuse bufA)
    gemm_mfma_k<<<gemmBlocks, 256, 0, stream>>>(h1, W2b, bufA, N_);
    agg2_k<<<(N_ + 3) / 4, 256, 0, stream>>>(bufA, ew, offsets, counts, dinv,
                                             b2, h1, N_);
    // head: h1 now holds jk = max(h1, h2); 64 nodes per block
    head_k<<<(N_ + 63) / 64, 256, 0, stream>>>(h1, Wf, bf, out, N_);
}